// Round 1
// baseline (2591.660 us; speedup 1.0000x reference)
//
#include <hip/hip_runtime.h>
#include <math.h>

#define NB 16
#define NSQ 512
#define NMAT (NB*NSQ)   // 8192
#define NF 1024         // 32*32
#define NSWEEP 10

// ---------------------------------------------------------------------------
// Kernel A: Cayley maps. C = (I - X)(I + X)^{-1}, X = W - W^T.
// Solve (I - X) Y = (I + X)  ->  Y = C^T  (since (I-X)^T = I+X for skew X).
// Gauss-Jordan without pivoting: I-X has all leading principal minors >= 1.
// ---------------------------------------------------------------------------
__global__ __launch_bounds__(64) void cayley_kernel(
    const float* __restrict__ qw, const float* __restrict__ kw,
    const float* __restrict__ vw, float* __restrict__ Cout) {
  __shared__ float M[32][33];
  __shared__ float R[32][33];
  __shared__ float fac[32];
  const float* W = (blockIdx.x == 0) ? qw : ((blockIdx.x == 1) ? kw : vw);
  const int t = threadIdx.x;
  for (int idx = t; idx < 1024; idx += 64) {
    int i = idx >> 5, j = idx & 31;
    float xv = W[i*32+j] - W[j*32+i];
    float d = (i == j) ? 1.0f : 0.0f;
    M[i][j] = d - xv;
    R[i][j] = d + xv;
  }
  __syncthreads();
  for (int k = 0; k < 32; ++k) {
    float inv = 1.0f / M[k][k];
    __syncthreads();
    if (t < 32) M[k][t] *= inv; else R[k][t-32] *= inv;
    __syncthreads();
    if (t < 32) fac[t] = M[t][k];
    __syncthreads();
    if (t < 32) {
      float mk = M[k][t];
      for (int i = 0; i < 32; ++i) {
        if (i == k) continue;
        M[i][t] -= fac[i] * mk;
      }
    } else {
      int tc = t - 32;
      float rk = R[k][tc];
      for (int i = 0; i < 32; ++i) {
        if (i == k) continue;
        R[i][tc] -= fac[i] * rk;
      }
    }
    __syncthreads();
  }
  // R = C^T ; store C row-major: C[p][q] = R[q][p]
  for (int idx = t; idx < 1024; idx += 64) {
    int p = idx >> 5, q = idx & 31;
    Cout[blockIdx.x * 1024 + idx] = R[q][p];
  }
}

// ---------------------------------------------------------------------------
// Kernel B: per-matrix symmetric eigendecomposition (parallel Jacobi, XOR
// pairing), then S = V log(w) V^T with zero diagonal, then the three
// conjugations q/k/v = offdiag(C S C^T), plus q2/k2 Frobenius norms.
// One 64-thread (single wave) block per matrix.
// ---------------------------------------------------------------------------
__global__ __launch_bounds__(64) void logm_qkv_kernel(
    const float* __restrict__ x, const float* __restrict__ Cm,
    float* __restrict__ qo, float* __restrict__ ko, float* __restrict__ vo,
    float* __restrict__ q2, float* __restrict__ k2) {
  __shared__ float A[32*33];
  __shared__ float V[32*33];
  __shared__ float T[32*33];
  __shared__ float cs_c[16], cs_s[16];
  __shared__ float logw[32];
  const int t = threadIdx.x;
  const int m = blockIdx.x;
  const float* xm = x + (size_t)m * NF;
  for (int idx = t; idx < 1024; idx += 64) {
    int i = idx >> 5, j = idx & 31;
    A[i*33+j] = xm[idx];
    V[i*33+j] = (i == j) ? 1.0f : 0.0f;
  }
  __syncthreads();
  const int ilane = t & 31;
  const int hi = t >> 5;
  for (int sw = 0; sw < NSWEEP; ++sw) {
    for (int r = 1; r < 32; ++r) {
      const int h = 31 - __builtin_clz((unsigned)r);
      const int lowmask = (1 << h) - 1;
      // phase 1: rotation angles for the 16 disjoint pairs {p, p^r}
      if (t < 16) {
        int p = ((t >> h) << (h+1)) | (t & lowmask);
        int q = p ^ r;
        float apq = A[p*33+q];
        float c = 1.0f, s = 0.0f;
        if (fabsf(apq) > 1e-36f) {
          float app = A[p*33+p];
          float aqq = A[q*33+q];
          float tau = (aqq - app) / (2.0f * apq);
          float tt = 1.0f / (fabsf(tau) + sqrtf(1.0f + tau*tau));
          tt = (tau < 0.0f) ? -tt : tt;
          c = 1.0f / sqrtf(1.0f + tt*tt);
          s = tt * c;
        }
        cs_c[t] = c; cs_s[t] = s;
      }
      __syncthreads();
      // phase 2: row rotations (B = J^T A). thread(hi,ilane), pair j=2k+hi, col ilane
      #pragma unroll
      for (int k = 0; k < 8; ++k) {
        int j = 2*k + hi;
        int p = ((j >> h) << (h+1)) | (j & lowmask);
        int q = p ^ r;
        float c = cs_c[j], s = cs_s[j];
        float ap = A[p*33+ilane], aq = A[q*33+ilane];
        A[p*33+ilane] = c*ap - s*aq;
        A[q*33+ilane] = fmaf(s, ap, c*aq);
      }
      __syncthreads();
      // phase 3: column rotations (A = B J) + eigenvector accumulation V = V J
      #pragma unroll
      for (int k = 0; k < 8; ++k) {
        int j = 2*k + hi;
        int p = ((j >> h) << (h+1)) | (j & lowmask);
        int q = p ^ r;
        float c = cs_c[j], s = cs_s[j];
        float ap = A[ilane*33+p], aq = A[ilane*33+q];
        A[ilane*33+p] = c*ap - s*aq;
        A[ilane*33+q] = fmaf(s, ap, c*aq);
        float vp = V[ilane*33+p], vq = V[ilane*33+q];
        V[ilane*33+p] = c*vp - s*vq;
        V[ilane*33+q] = fmaf(s, vp, c*vq);
      }
      __syncthreads();
    }
  }
  if (t < 32) logw[t] = logf(fmaxf(A[t*33+t], 1e-30f));
  __syncthreads();
  // S = V diag(logw) V^T, zero diagonal (olm_diffeo) -> T
  for (int idx = t; idx < 1024; idx += 64) {
    int i = idx >> 5, j = idx & 31;
    float acc = 0.0f;
    #pragma unroll
    for (int kk = 0; kk < 32; ++kk)
      acc = fmaf(V[i*33+kk] * logw[kk], V[j*33+kk], acc);
    T[i*33+j] = (i == j) ? 0.0f : acc;
  }
  __syncthreads();
  // q/k/v = offdiag(C S C^T); C in A, T1 = C@S in V
  for (int w = 0; w < 3; ++w) {
    for (int idx = t; idx < 1024; idx += 64) {
      A[idx + (idx >> 5)] = Cm[w*1024 + idx];   // A[i*33+j], i=idx>>5, j=idx&31
    }
    __syncthreads();
    for (int idx = t; idx < 1024; idx += 64) {
      int i = idx >> 5, j = idx & 31;
      float acc = 0.0f;
      #pragma unroll
      for (int kk = 0; kk < 32; ++kk)
        acc = fmaf(A[i*33+kk], T[kk*33+j], acc);
      V[i*33+j] = acc;
    }
    __syncthreads();
    float ss = 0.0f;
    float* outp = (w == 0) ? qo : ((w == 1) ? ko : vo);
    for (int idx = t; idx < 1024; idx += 64) {
      int i = idx >> 5, j = idx & 31;
      float acc = 0.0f;
      #pragma unroll
      for (int kk = 0; kk < 32; ++kk)
        acc = fmaf(V[i*33+kk], A[j*33+kk], acc);
      if (i == j) acc = 0.0f;
      outp[(size_t)m*NF + idx] = acc;
      ss = fmaf(acc, acc, ss);
    }
    if (w < 2) {
      #pragma unroll
      for (int off = 32; off > 0; off >>= 1)
        ss += __shfl_down(ss, off);
      if (t == 0) ((w == 0) ? q2 : k2)[m] = ss;
    }
    __syncthreads();
  }
}

// ---------------------------------------------------------------------------
// Kernel C1: G[b,j,i] = <kf[b,j], qf[b,i]> (K=1024), fused scores epilogue.
// 64x64 tile, 256 threads, 4x4 per thread, fp32.
// ---------------------------------------------------------------------------
__global__ __launch_bounds__(256) void scores_kernel(
    const float* __restrict__ qf, const float* __restrict__ kf,
    const float* __restrict__ q2, const float* __restrict__ k2,
    float* __restrict__ P) {
  __shared__ float Ks[64][17];
  __shared__ float Qs[64][17];
  const int b = blockIdx.z;
  const int j0 = blockIdx.y * 64;
  const int i0 = blockIdx.x * 64;
  const int tx = threadIdx.x & 15, ty = threadIdx.x >> 4;
  const int lrow = threadIdx.x >> 2;
  const int lc4 = (threadIdx.x & 3) * 4;
  float acc[4][4] = {};
  const float* kb = kf + (size_t)(b*NSQ + j0) * NF;
  const float* qb = qf + (size_t)(b*NSQ + i0) * NF;
  for (int f0 = 0; f0 < NF; f0 += 16) {
    float4 kv = *(const float4*)(kb + (size_t)lrow*NF + f0 + lc4);
    float4 qv = *(const float4*)(qb + (size_t)lrow*NF + f0 + lc4);
    Ks[lrow][lc4+0] = kv.x; Ks[lrow][lc4+1] = kv.y; Ks[lrow][lc4+2] = kv.z; Ks[lrow][lc4+3] = kv.w;
    Qs[lrow][lc4+0] = qv.x; Qs[lrow][lc4+1] = qv.y; Qs[lrow][lc4+2] = qv.z; Qs[lrow][lc4+3] = qv.w;
    __syncthreads();
    #pragma unroll
    for (int kk = 0; kk < 16; ++kk) {
      float a0 = Ks[ty*4+0][kk], a1 = Ks[ty*4+1][kk], a2 = Ks[ty*4+2][kk], a3 = Ks[ty*4+3][kk];
      float b0 = Qs[tx*4+0][kk], b1 = Qs[tx*4+1][kk], b2 = Qs[tx*4+2][kk], b3 = Qs[tx*4+3][kk];
      acc[0][0]=fmaf(a0,b0,acc[0][0]); acc[0][1]=fmaf(a0,b1,acc[0][1]);
      acc[0][2]=fmaf(a0,b2,acc[0][2]); acc[0][3]=fmaf(a0,b3,acc[0][3]);
      acc[1][0]=fmaf(a1,b0,acc[1][0]); acc[1][1]=fmaf(a1,b1,acc[1][1]);
      acc[1][2]=fmaf(a1,b2,acc[1][2]); acc[1][3]=fmaf(a1,b3,acc[1][3]);
      acc[2][0]=fmaf(a2,b0,acc[2][0]); acc[2][1]=fmaf(a2,b1,acc[2][1]);
      acc[2][2]=fmaf(a2,b2,acc[2][2]); acc[2][3]=fmaf(a2,b3,acc[2][3]);
      acc[3][0]=fmaf(a3,b0,acc[3][0]); acc[3][1]=fmaf(a3,b1,acc[3][1]);
      acc[3][2]=fmaf(a3,b2,acc[3][2]); acc[3][3]=fmaf(a3,b3,acc[3][3]);
    }
    __syncthreads();
  }
  #pragma unroll
  for (int u = 0; u < 4; ++u) {
    int j = j0 + ty*4 + u;
    float kj = k2[b*NSQ + j];
    #pragma unroll
    for (int vv = 0; vv < 4; ++vv) {
      int i = i0 + tx*4 + vv;
      float d2 = kj + q2[b*NSQ + i] - 2.0f * acc[u][vv];
      float e = sqrtf(fmaxf(d2, 1e-12f));
      float sc = 1.0f / (1.0f + log1pf(e));
      P[(size_t)(b*NSQ + j)*NSQ + i] = sc;
    }
  }
}

// ---------------------------------------------------------------------------
// Kernel C1b: softmax over j (axis -2) for each (b,i) column, in place.
// ---------------------------------------------------------------------------
__global__ __launch_bounds__(256) void softmax_kernel(float* __restrict__ P) {
  __shared__ float red[4][64];
  const int b = blockIdx.x >> 3;
  const int i0 = (blockIdx.x & 7) * 64;
  const int il = threadIdx.x & 63;
  const int jg = threadIdx.x >> 6;   // 0..3
  float* base = P + (size_t)b*NSQ*NSQ + i0 + il;
  float mx = -1e30f;
  for (int j = jg*128; j < jg*128 + 128; ++j)
    mx = fmaxf(mx, base[(size_t)j*NSQ]);
  red[jg][il] = mx;
  __syncthreads();
  float cm = fmaxf(fmaxf(red[0][il], red[1][il]), fmaxf(red[2][il], red[3][il]));
  float ssum = 0.0f;
  for (int j = jg*128; j < jg*128 + 128; ++j)
    ssum += expf(base[(size_t)j*NSQ] - cm);
  __syncthreads();
  red[jg][il] = ssum;
  __syncthreads();
  float inv = 1.0f / (red[0][il] + red[1][il] + red[2][il] + red[3][il]);
  for (int j = jg*128; j < jg*128 + 128; ++j) {
    size_t o = (size_t)j*NSQ;
    base[o] = expf(base[o] - cm) * inv;
  }
}

// ---------------------------------------------------------------------------
// Kernel C2: out[b,c,f] = sum_a P[b,c,a] * vf[b,a,f]   (NN GEMM, K=512)
// ---------------------------------------------------------------------------
__global__ __launch_bounds__(256) void out_gemm_kernel(
    const float* __restrict__ P, const float* __restrict__ vf,
    float* __restrict__ out) {
  __shared__ float Ps[64][17];
  __shared__ float Vs[16][68];
  const int b = blockIdx.z;
  const int c0 = blockIdx.y * 64;
  const int f0 = blockIdx.x * 64;
  const int tx = threadIdx.x & 15, ty = threadIdx.x >> 4;
  float acc[4][4] = {};
  const float* Pb = P + (size_t)b * NSQ * NSQ;
  const float* Vb = vf + (size_t)b * NSQ * NF;
  for (int a0 = 0; a0 < NSQ; a0 += 16) {
    {
      int row = threadIdx.x >> 2;
      int c4 = (threadIdx.x & 3) * 4;
      float4 pv = *(const float4*)(Pb + (size_t)(c0 + row) * NSQ + a0 + c4);
      Ps[row][c4+0]=pv.x; Ps[row][c4+1]=pv.y; Ps[row][c4+2]=pv.z; Ps[row][c4+3]=pv.w;
    }
    {
      int row = threadIdx.x >> 4;
      int c4 = (threadIdx.x & 15) * 4;
      float4 vv4 = *(const float4*)(Vb + (size_t)(a0 + row) * NF + f0 + c4);
      Vs[row][c4+0]=vv4.x; Vs[row][c4+1]=vv4.y; Vs[row][c4+2]=vv4.z; Vs[row][c4+3]=vv4.w;
    }
    __syncthreads();
    #pragma unroll
    for (int kk = 0; kk < 16; ++kk) {
      float a0r = Ps[ty*4+0][kk], a1r = Ps[ty*4+1][kk], a2r = Ps[ty*4+2][kk], a3r = Ps[ty*4+3][kk];
      float b0 = Vs[kk][tx*4+0], b1 = Vs[kk][tx*4+1], b2 = Vs[kk][tx*4+2], b3 = Vs[kk][tx*4+3];
      acc[0][0]=fmaf(a0r,b0,acc[0][0]); acc[0][1]=fmaf(a0r,b1,acc[0][1]);
      acc[0][2]=fmaf(a0r,b2,acc[0][2]); acc[0][3]=fmaf(a0r,b3,acc[0][3]);
      acc[1][0]=fmaf(a1r,b0,acc[1][0]); acc[1][1]=fmaf(a1r,b1,acc[1][1]);
      acc[1][2]=fmaf(a1r,b2,acc[1][2]); acc[1][3]=fmaf(a1r,b3,acc[1][3]);
      acc[2][0]=fmaf(a2r,b0,acc[2][0]); acc[2][1]=fmaf(a2r,b1,acc[2][1]);
      acc[2][2]=fmaf(a2r,b2,acc[2][2]); acc[2][3]=fmaf(a2r,b3,acc[2][3]);
      acc[3][0]=fmaf(a3r,b0,acc[3][0]); acc[3][1]=fmaf(a3r,b1,acc[3][1]);
      acc[3][2]=fmaf(a3r,b2,acc[3][2]); acc[3][3]=fmaf(a3r,b3,acc[3][3]);
    }
    __syncthreads();
  }
  #pragma unroll
  for (int u = 0; u < 4; ++u) {
    float4 o;
    o.x = acc[u][0]; o.y = acc[u][1]; o.z = acc[u][2]; o.w = acc[u][3];
    *(float4*)(out + (size_t)(b*NSQ + c0 + ty*4 + u) * NF + f0 + tx*4) = o;
  }
}

extern "C" void kernel_launch(void* const* d_in, const int* in_sizes, int n_in,
                              void* d_out, int out_size, void* d_ws, size_t ws_size,
                              hipStream_t stream) {
  const float* x  = (const float*)d_in[0];
  const float* qw = (const float*)d_in[1];
  const float* kw = (const float*)d_in[2];
  const float* vw = (const float*)d_in[3];
  float* ws = (float*)d_ws;
  // ws layout (floats): C[3*1024] | q[8192*1024] | k | v | q2[8192] | k2[8192] | P[16*512*512]
  float* C  = ws;
  float* q  = ws + 3072;
  float* k  = q + (size_t)NMAT * NF;
  float* v  = k + (size_t)NMAT * NF;
  float* q2 = v + (size_t)NMAT * NF;
  float* k2 = q2 + NMAT;
  float* P  = k2 + NMAT;
  float* out = (float*)d_out;

  cayley_kernel<<<dim3(3), dim3(64), 0, stream>>>(qw, kw, vw, C);
  logm_qkv_kernel<<<dim3(NMAT), dim3(64), 0, stream>>>(x, C, q, k, v, q2, k2);
  scores_kernel<<<dim3(8, 8, NB), dim3(256), 0, stream>>>(q, k, q2, k2, P);
  softmax_kernel<<<dim3(NB * 8), dim3(256), 0, stream>>>(P);
  out_gemm_kernel<<<dim3(16, 8, NB), dim3(256), 0, stream>>>(P, v, out);
}

// Round 2
// 1630.661 us; speedup vs baseline: 1.5893x; 1.5893x over previous
//
#include <hip/hip_runtime.h>
#include <math.h>

#define NB 16
#define NSQ 512
#define NMAT (NB*NSQ)   // 8192
#define NF 1024         // 32*32
#define NSWEEP 8
#define SB 36           // LDS row stride (floats): 144B = multiple of 16 -> b128-aligned rows

// ---------------------------------------------------------------------------
// Kernel A: Cayley maps. C = (I - X)(I + X)^{-1}, X = W - W^T.
// ---------------------------------------------------------------------------
__global__ __launch_bounds__(64) void cayley_kernel(
    const float* __restrict__ qw, const float* __restrict__ kw,
    const float* __restrict__ vw, float* __restrict__ Cout) {
  __shared__ float M[32][33];
  __shared__ float R[32][33];
  __shared__ float fac[32];
  const float* W = (blockIdx.x == 0) ? qw : ((blockIdx.x == 1) ? kw : vw);
  const int t = threadIdx.x;
  for (int idx = t; idx < 1024; idx += 64) {
    int i = idx >> 5, j = idx & 31;
    float xv = W[i*32+j] - W[j*32+i];
    float d = (i == j) ? 1.0f : 0.0f;
    M[i][j] = d - xv;
    R[i][j] = d + xv;
  }
  __syncthreads();
  for (int k = 0; k < 32; ++k) {
    float inv = 1.0f / M[k][k];
    __syncthreads();
    if (t < 32) M[k][t] *= inv; else R[k][t-32] *= inv;
    __syncthreads();
    if (t < 32) fac[t] = M[t][k];
    __syncthreads();
    if (t < 32) {
      float mk = M[k][t];
      for (int i = 0; i < 32; ++i) {
        if (i == k) continue;
        M[i][t] -= fac[i] * mk;
      }
    } else {
      int tc = t - 32;
      float rk = R[k][tc];
      for (int i = 0; i < 32; ++i) {
        if (i == k) continue;
        R[i][tc] -= fac[i] * rk;
      }
    }
    __syncthreads();
  }
  // R = C^T ; store C row-major: C[p][q] = R[q][p]
  for (int idx = t; idx < 1024; idx += 64) {
    int p = idx >> 5, q = idx & 31;
    Cout[blockIdx.x * 1024 + idx] = R[q][p];
  }
}

// ---------------------------------------------------------------------------
// Kernel B: per-matrix sym eigendecomposition (parallel Jacobi, XOR pairing,
// blocked 2x2 update), then S = V log(w) V^T (zero diag), then the three
// conjugations q/k/v = offdiag(C S C^T) + q2/k2 norms.
// One 64-thread (single wave) block per matrix. LDS-pipe-count optimized:
//  - A' = J^T A J done as 256 independent 2x2 blocks: 4 reads + 4 writes each
//  - V kept TRANSPOSED; V^T <- J^T V^T = contiguous row rotations via float4
//  - epilogue: all matmuls are row.row dots (symmetry), 4x4 tiles, b128 reads
// ---------------------------------------------------------------------------
__global__ __launch_bounds__(64) void logm_qkv_kernel(
    const float* __restrict__ x, const float* __restrict__ Cm,
    float* __restrict__ qo, float* __restrict__ ko, float* __restrict__ vo,
    float* __restrict__ q2, float* __restrict__ k2) {
  __shared__ __align__(16) float buf0[32*SB];   // A -> Vrow -> C
  __shared__ __align__(16) float buf1[32*SB];   // Vt -> T (=offdiag S)
  __shared__ __align__(16) float buf2[32*SB];   // U
  __shared__ __align__(16) float2 cs[16];
  __shared__ __align__(16) float lw[32];
  const int t = threadIdx.x;
  const int m = blockIdx.x;
  const float* xm = x + (size_t)m * NF;

  // init A = x (stride SB, b128) and Vt = I
  #pragma unroll
  for (int s = 0; s < 4; ++s) {
    int fi = t + 64*s;               // float4 index 0..255
    int i = fi >> 3, j4 = (fi & 7) << 2;
    float4 xv = *(const float4*)&xm[(size_t)fi*4];
    *(float4*)&buf0[i*SB + j4] = xv;
    float4 iv;
    iv.x = (i == j4+0) ? 1.0f : 0.0f;
    iv.y = (i == j4+1) ? 1.0f : 0.0f;
    iv.z = (i == j4+2) ? 1.0f : 0.0f;
    iv.w = (i == j4+3) ? 1.0f : 0.0f;
    *(float4*)&buf1[i*SB + j4] = iv;
  }
  __syncthreads();

  for (int sw = 0; sw < NSWEEP; ++sw) {
    for (int r = 1; r < 32; ++r) {
      const int h = 31 - __builtin_clz((unsigned)r);
      const int lowmask = (1 << h) - 1;
      // phase 1: rotation angles for the 16 disjoint pairs {p, p^r}
      if (t < 16) {
        int p = ((t >> h) << (h+1)) | (t & lowmask);
        int q = p ^ r;
        float apq = buf0[p*SB+q];
        float c = 1.0f, s = 0.0f;
        if (fabsf(apq) > 1e-36f) {
          float app = buf0[p*SB+p];
          float aqq = buf0[q*SB+q];
          float tau = (aqq - app) / (2.0f * apq);
          float tt = 1.0f / (fabsf(tau) + sqrtf(1.0f + tau*tau));
          tt = (tau < 0.0f) ? -tt : tt;
          c = 1.0f / sqrtf(1.0f + tt*tt);
          s = tt * c;
        }
        cs[t] = make_float2(c, s);
      }
      __syncthreads();
      // phase 2: blocked A update. Block (a,b) = rows {pa,qa} x cols {pb,qb};
      // blocks are disjoint -> no intra-phase hazards, no barrier needed.
      {
        const int b = t & 15;
        const int pb = ((b >> h) << (h+1)) | (b & lowmask);
        const int qb = pb ^ r;
        const float2 csb = cs[b];
        const int ab = t >> 4;
        #pragma unroll
        for (int u = 0; u < 4; ++u) {
          int a = ab + 4*u;
          int pa = ((a >> h) << (h+1)) | (a & lowmask);
          int qa = pa ^ r;
          float2 csa = cs[a];
          float* rp = buf0 + pa*SB;
          float* rq = buf0 + qa*SB;
          float x11 = rp[pb], x12 = rp[qb];
          float x21 = rq[pb], x22 = rq[qb];
          // left rotation (rows, pair a): B = J^T A
          float y11 = csa.x*x11 - csa.y*x21;
          float y12 = csa.x*x12 - csa.y*x22;
          float y21 = fmaf(csa.y, x11, csa.x*x21);
          float y22 = fmaf(csa.y, x12, csa.x*x22);
          // right rotation (cols, pair b): A' = B J
          rp[pb] = csb.x*y11 - csb.y*y12;
          rp[qb] = fmaf(csb.y, y11, csb.x*y12);
          rq[pb] = csb.x*y21 - csb.y*y22;
          rq[qb] = fmaf(csb.y, y21, csb.x*y22);
        }
        // V^T row rotations (V = V J  <=>  Vt = J^T Vt), float4 chunks
        #pragma unroll
        for (int vtk = 0; vtk < 2; ++vtk) {
          int tsk = t + 64*vtk;
          int pr = tsk >> 3;               // pair 0..15
          int ch = (tsk & 7) << 2;         // column chunk
          int p = ((pr >> h) << (h+1)) | (pr & lowmask);
          int q = p ^ r;
          float2 c2 = cs[pr];
          float4 vp = *(float4*)&buf1[p*SB + ch];
          float4 vq = *(float4*)&buf1[q*SB + ch];
          float4 np, nq;
          np.x = c2.x*vp.x - c2.y*vq.x;  nq.x = fmaf(c2.y, vp.x, c2.x*vq.x);
          np.y = c2.x*vp.y - c2.y*vq.y;  nq.y = fmaf(c2.y, vp.y, c2.x*vq.y);
          np.z = c2.x*vp.z - c2.y*vq.z;  nq.z = fmaf(c2.y, vp.z, c2.x*vq.z);
          np.w = c2.x*vp.w - c2.y*vq.w;  nq.w = fmaf(c2.y, vp.w, c2.x*vq.w);
          *(float4*)&buf1[p*SB + ch] = np;
          *(float4*)&buf1[q*SB + ch] = nq;
        }
      }
      __syncthreads();
    }
  }

  if (t < 32) lw[t] = logf(fmaxf(buf0[t*SB+t], 1e-30f));
  __syncthreads();
  // transpose Vt(buf1) -> Vrow(buf0): Vrow[i][k] = V[i][k] row-contiguous
  #pragma unroll
  for (int s = 0; s < 16; ++s) {
    int idx = t + 64*s;
    int i = idx >> 5, k = idx & 31;
    buf0[i*SB + k] = buf1[k*SB + i];
  }
  __syncthreads();

  const int rg = t >> 3, cg = t & 7;
  const int i0 = rg*4, j0 = cg*4;
  // T = offdiag(S), S[i][j] = sum_k (Vrow[i][k]*lw[k]) * Vrow[j][k]  -> buf1
  {
    float acc[4][4] = {};
    #pragma unroll
    for (int k4 = 0; k4 < 32; k4 += 4) {
      float4 lv = *(float4*)&lw[k4];
      float4 av[4], bv[4];
      #pragma unroll
      for (int d = 0; d < 4; ++d) {
        float4 a4 = *(float4*)&buf0[(i0+d)*SB + k4];
        av[d].x = a4.x*lv.x; av[d].y = a4.y*lv.y; av[d].z = a4.z*lv.z; av[d].w = a4.w*lv.w;
        bv[d] = *(float4*)&buf0[(j0+d)*SB + k4];
      }
      #pragma unroll
      for (int d = 0; d < 4; ++d)
        #pragma unroll
        for (int e = 0; e < 4; ++e) {
          acc[d][e] = fmaf(av[d].x, bv[e].x, acc[d][e]);
          acc[d][e] = fmaf(av[d].y, bv[e].y, acc[d][e]);
          acc[d][e] = fmaf(av[d].z, bv[e].z, acc[d][e]);
          acc[d][e] = fmaf(av[d].w, bv[e].w, acc[d][e]);
        }
    }
    #pragma unroll
    for (int d = 0; d < 4; ++d) {
      if (rg == cg) acc[d][d] = 0.0f;
      float4 z; z.x = acc[d][0]; z.y = acc[d][1]; z.z = acc[d][2]; z.w = acc[d][3];
      *(float4*)&buf1[(i0+d)*SB + j0] = z;
    }
  }
  __syncthreads();

  for (int w = 0; w < 3; ++w) {
    const float* Cw = Cm + w*1024;
    // load C -> buf0 (b128 both sides)
    #pragma unroll
    for (int s = 0; s < 4; ++s) {
      int fi = t + 64*s;
      int i = fi >> 3, c4 = (fi & 7) << 2;
      *(float4*)&buf0[i*SB + c4] = *(const float4*)&Cw[fi*4];
    }
    __syncthreads();
    // U = C * T (T symmetric): U[i][j] = sum_k C[i][k] * T[j][k] -> buf2
    {
      float acc[4][4] = {};
      #pragma unroll
      for (int k4 = 0; k4 < 32; k4 += 4) {
        float4 av[4], bv[4];
        #pragma unroll
        for (int d = 0; d < 4; ++d) {
          av[d] = *(float4*)&buf0[(i0+d)*SB + k4];
          bv[d] = *(float4*)&buf1[(j0+d)*SB + k4];
        }
        #pragma unroll
        for (int d = 0; d < 4; ++d)
          #pragma unroll
          for (int e = 0; e < 4; ++e) {
            acc[d][e] = fmaf(av[d].x, bv[e].x, acc[d][e]);
            acc[d][e] = fmaf(av[d].y, bv[e].y, acc[d][e]);
            acc[d][e] = fmaf(av[d].z, bv[e].z, acc[d][e]);
            acc[d][e] = fmaf(av[d].w, bv[e].w, acc[d][e]);
          }
      }
      #pragma unroll
      for (int d = 0; d < 4; ++d) {
        float4 z; z.x = acc[d][0]; z.y = acc[d][1]; z.z = acc[d][2]; z.w = acc[d][3];
        *(float4*)&buf2[(i0+d)*SB + j0] = z;
      }
    }
    __syncthreads();
    // Z = U * C^T: Z[i][j] = sum_k U[i][k] * C[j][k]; offdiag -> global
    {
      float acc[4][4] = {};
      #pragma unroll
      for (int k4 = 0; k4 < 32; k4 += 4) {
        float4 av[4], bv[4];
        #pragma unroll
        for (int d = 0; d < 4; ++d) {
          av[d] = *(float4*)&buf2[(i0+d)*SB + k4];
          bv[d] = *(float4*)&buf0[(j0+d)*SB + k4];
        }
        #pragma unroll
        for (int d = 0; d < 4; ++d)
          #pragma unroll
          for (int e = 0; e < 4; ++e) {
            acc[d][e] = fmaf(av[d].x, bv[e].x, acc[d][e]);
            acc[d][e] = fmaf(av[d].y, bv[e].y, acc[d][e]);
            acc[d][e] = fmaf(av[d].z, bv[e].z, acc[d][e]);
            acc[d][e] = fmaf(av[d].w, bv[e].w, acc[d][e]);
          }
      }
      float ss = 0.0f;
      float* outp = (w == 0) ? qo : ((w == 1) ? ko : vo);
      #pragma unroll
      for (int d = 0; d < 4; ++d) {
        if (rg == cg) acc[d][d] = 0.0f;
        ss = fmaf(acc[d][0], acc[d][0], ss);
        ss = fmaf(acc[d][1], acc[d][1], ss);
        ss = fmaf(acc[d][2], acc[d][2], ss);
        ss = fmaf(acc[d][3], acc[d][3], ss);
        float4 z; z.x = acc[d][0]; z.y = acc[d][1]; z.z = acc[d][2]; z.w = acc[d][3];
        *(float4*)&outp[(size_t)m*NF + (i0+d)*32 + j0] = z;
      }
      if (w < 2) {
        #pragma unroll
        for (int off = 32; off > 0; off >>= 1)
          ss += __shfl_down(ss, off);
        if (t == 0) ((w == 0) ? q2 : k2)[m] = ss;
      }
    }
    __syncthreads();
  }
}

// ---------------------------------------------------------------------------
// Kernel C1: G[b,j,i] = <kf[b,j], qf[b,i]> (K=1024), fused scores epilogue.
// ---------------------------------------------------------------------------
__global__ __launch_bounds__(256) void scores_kernel(
    const float* __restrict__ qf, const float* __restrict__ kf,
    const float* __restrict__ q2, const float* __restrict__ k2,
    float* __restrict__ P) {
  __shared__ float Ks[64][17];
  __shared__ float Qs[64][17];
  const int b = blockIdx.z;
  const int j0 = blockIdx.y * 64;
  const int i0 = blockIdx.x * 64;
  const int tx = threadIdx.x & 15, ty = threadIdx.x >> 4;
  const int lrow = threadIdx.x >> 2;
  const int lc4 = (threadIdx.x & 3) * 4;
  float acc[4][4] = {};
  const float* kb = kf + (size_t)(b*NSQ + j0) * NF;
  const float* qb = qf + (size_t)(b*NSQ + i0) * NF;
  for (int f0 = 0; f0 < NF; f0 += 16) {
    float4 kv = *(const float4*)(kb + (size_t)lrow*NF + f0 + lc4);
    float4 qv = *(const float4*)(qb + (size_t)lrow*NF + f0 + lc4);
    Ks[lrow][lc4+0] = kv.x; Ks[lrow][lc4+1] = kv.y; Ks[lrow][lc4+2] = kv.z; Ks[lrow][lc4+3] = kv.w;
    Qs[lrow][lc4+0] = qv.x; Qs[lrow][lc4+1] = qv.y; Qs[lrow][lc4+2] = qv.z; Qs[lrow][lc4+3] = qv.w;
    __syncthreads();
    #pragma unroll
    for (int kk = 0; kk < 16; ++kk) {
      float a0 = Ks[ty*4+0][kk], a1 = Ks[ty*4+1][kk], a2 = Ks[ty*4+2][kk], a3 = Ks[ty*4+3][kk];
      float b0 = Qs[tx*4+0][kk], b1 = Qs[tx*4+1][kk], b2 = Qs[tx*4+2][kk], b3 = Qs[tx*4+3][kk];
      acc[0][0]=fmaf(a0,b0,acc[0][0]); acc[0][1]=fmaf(a0,b1,acc[0][1]);
      acc[0][2]=fmaf(a0,b2,acc[0][2]); acc[0][3]=fmaf(a0,b3,acc[0][3]);
      acc[1][0]=fmaf(a1,b0,acc[1][0]); acc[1][1]=fmaf(a1,b1,acc[1][1]);
      acc[1][2]=fmaf(a1,b2,acc[1][2]); acc[1][3]=fmaf(a1,b3,acc[1][3]);
      acc[2][0]=fmaf(a2,b0,acc[2][0]); acc[2][1]=fmaf(a2,b1,acc[2][1]);
      acc[2][2]=fmaf(a2,b2,acc[2][2]); acc[2][3]=fmaf(a2,b3,acc[2][3]);
      acc[3][0]=fmaf(a3,b0,acc[3][0]); acc[3][1]=fmaf(a3,b1,acc[3][1]);
      acc[3][2]=fmaf(a3,b2,acc[3][2]); acc[3][3]=fmaf(a3,b3,acc[3][3]);
    }
    __syncthreads();
  }
  #pragma unroll
  for (int u = 0; u < 4; ++u) {
    int j = j0 + ty*4 + u;
    float kj = k2[b*NSQ + j];
    #pragma unroll
    for (int vv = 0; vv < 4; ++vv) {
      int i = i0 + tx*4 + vv;
      float d2 = kj + q2[b*NSQ + i] - 2.0f * acc[u][vv];
      float e = sqrtf(fmaxf(d2, 1e-12f));
      float sc = 1.0f / (1.0f + log1pf(e));
      P[(size_t)(b*NSQ + j)*NSQ + i] = sc;
    }
  }
}

// ---------------------------------------------------------------------------
// Kernel C1b: softmax over j (axis -2) for each (b,i) column, in place.
// ---------------------------------------------------------------------------
__global__ __launch_bounds__(256) void softmax_kernel(float* __restrict__ P) {
  __shared__ float red[4][64];
  const int b = blockIdx.x >> 3;
  const int i0 = (blockIdx.x & 7) * 64;
  const int il = threadIdx.x & 63;
  const int jg = threadIdx.x >> 6;   // 0..3
  float* base = P + (size_t)b*NSQ*NSQ + i0 + il;
  float mx = -1e30f;
  for (int j = jg*128; j < jg*128 + 128; ++j)
    mx = fmaxf(mx, base[(size_t)j*NSQ]);
  red[jg][il] = mx;
  __syncthreads();
  float cm = fmaxf(fmaxf(red[0][il], red[1][il]), fmaxf(red[2][il], red[3][il]));
  float ssum = 0.0f;
  for (int j = jg*128; j < jg*128 + 128; ++j)
    ssum += expf(base[(size_t)j*NSQ] - cm);
  __syncthreads();
  red[jg][il] = ssum;
  __syncthreads();
  float inv = 1.0f / (red[0][il] + red[1][il] + red[2][il] + red[3][il]);
  for (int j = jg*128; j < jg*128 + 128; ++j) {
    size_t o = (size_t)j*NSQ;
    base[o] = expf(base[o] - cm) * inv;
  }
}

// ---------------------------------------------------------------------------
// Kernel C2: out[b,c,f] = sum_a P[b,c,a] * vf[b,a,f]   (NN GEMM, K=512)
// ---------------------------------------------------------------------------
__global__ __launch_bounds__(256) void out_gemm_kernel(
    const float* __restrict__ P, const float* __restrict__ vf,
    float* __restrict__ out) {
  __shared__ float Ps[64][17];
  __shared__ float Vs[16][68];
  const int b = blockIdx.z;
  const int c0 = blockIdx.y * 64;
  const int f0 = blockIdx.x * 64;
  const int tx = threadIdx.x & 15, ty = threadIdx.x >> 4;
  float acc[4][4] = {};
  const float* Pb = P + (size_t)b * NSQ * NSQ;
  const float* Vb = vf + (size_t)b * NSQ * NF;
  for (int a0 = 0; a0 < NSQ; a0 += 16) {
    {
      int row = threadIdx.x >> 2;
      int c4 = (threadIdx.x & 3) * 4;
      float4 pv = *(const float4*)(Pb + (size_t)(c0 + row) * NSQ + a0 + c4);
      Ps[row][c4+0]=pv.x; Ps[row][c4+1]=pv.y; Ps[row][c4+2]=pv.z; Ps[row][c4+3]=pv.w;
    }
    {
      int row = threadIdx.x >> 4;
      int c4 = (threadIdx.x & 15) * 4;
      float4 vv4 = *(const float4*)(Vb + (size_t)(a0 + row) * NF + f0 + c4);
      Vs[row][c4+0]=vv4.x; Vs[row][c4+1]=vv4.y; Vs[row][c4+2]=vv4.z; Vs[row][c4+3]=vv4.w;
    }
    __syncthreads();
    #pragma unroll
    for (int kk = 0; kk < 16; ++kk) {
      float a0r = Ps[ty*4+0][kk], a1r = Ps[ty*4+1][kk], a2r = Ps[ty*4+2][kk], a3r = Ps[ty*4+3][kk];
      float b0 = Vs[kk][tx*4+0], b1 = Vs[kk][tx*4+1], b2 = Vs[kk][tx*4+2], b3 = Vs[kk][tx*4+3];
      acc[0][0]=fmaf(a0r,b0,acc[0][0]); acc[0][1]=fmaf(a0r,b1,acc[0][1]);
      acc[0][2]=fmaf(a0r,b2,acc[0][2]); acc[0][3]=fmaf(a0r,b3,acc[0][3]);
      acc[1][0]=fmaf(a1r,b0,acc[1][0]); acc[1][1]=fmaf(a1r,b1,acc[1][1]);
      acc[1][2]=fmaf(a1r,b2,acc[1][2]); acc[1][3]=fmaf(a1r,b3,acc[1][3]);
      acc[2][0]=fmaf(a2r,b0,acc[2][0]); acc[2][1]=fmaf(a2r,b1,acc[2][1]);
      acc[2][2]=fmaf(a2r,b2,acc[2][2]); acc[2][3]=fmaf(a2r,b3,acc[2][3]);
      acc[3][0]=fmaf(a3r,b0,acc[3][0]); acc[3][1]=fmaf(a3r,b1,acc[3][1]);
      acc[3][2]=fmaf(a3r,b2,acc[3][2]); acc[3][3]=fmaf(a3r,b3,acc[3][3]);
    }
    __syncthreads();
  }
  #pragma unroll
  for (int u = 0; u < 4; ++u) {
    float4 o;
    o.x = acc[u][0]; o.y = acc[u][1]; o.z = acc[u][2]; o.w = acc[u][3];
    *(float4*)(out + (size_t)(b*NSQ + c0 + ty*4 + u) * NF + f0 + tx*4) = o;
  }
}

extern "C" void kernel_launch(void* const* d_in, const int* in_sizes, int n_in,
                              void* d_out, int out_size, void* d_ws, size_t ws_size,
                              hipStream_t stream) {
  const float* x  = (const float*)d_in[0];
  const float* qw = (const float*)d_in[1];
  const float* kw = (const float*)d_in[2];
  const float* vw = (const float*)d_in[3];
  float* ws = (float*)d_ws;
  float* C  = ws;
  float* q  = ws + 3072;
  float* k  = q + (size_t)NMAT * NF;
  float* v  = k + (size_t)NMAT * NF;
  float* q2 = v + (size_t)NMAT * NF;
  float* k2 = q2 + NMAT;
  float* P  = k2 + NMAT;
  float* out = (float*)d_out;

  cayley_kernel<<<dim3(3), dim3(64), 0, stream>>>(qw, kw, vw, C);
  logm_qkv_kernel<<<dim3(NMAT), dim3(64), 0, stream>>>(x, C, q, k, v, q2, k2);
  scores_kernel<<<dim3(8, 8, NB), dim3(256), 0, stream>>>(q, k, q2, k2, P);
  softmax_kernel<<<dim3(NB * 8), dim3(256), 0, stream>>>(P);
  out_gemm_kernel<<<dim3(16, 8, NB), dim3(256), 0, stream>>>(P, v, out);
}

// Round 3
// 1550.500 us; speedup vs baseline: 1.6715x; 1.0517x over previous
//
#include <hip/hip_runtime.h>
#include <math.h>

#define NB 16
#define NSQ 512
#define NMAT (NB*NSQ)   // 8192
#define NF 1024         // 32*32
#define NSWEEP 7
#define SB 36           // LDS row stride (floats): 144B = multiple of 16 -> b128-aligned rows

// ---------------------------------------------------------------------------
// Kernel A: Cayley maps. C = (I - X)(I + X)^{-1}, X = W - W^T.
// ---------------------------------------------------------------------------
__global__ __launch_bounds__(64) void cayley_kernel(
    const float* __restrict__ qw, const float* __restrict__ kw,
    const float* __restrict__ vw, float* __restrict__ Cout) {
  __shared__ float M[32][33];
  __shared__ float R[32][33];
  __shared__ float fac[32];
  const float* W = (blockIdx.x == 0) ? qw : ((blockIdx.x == 1) ? kw : vw);
  const int t = threadIdx.x;
  for (int idx = t; idx < 1024; idx += 64) {
    int i = idx >> 5, j = idx & 31;
    float xv = W[i*32+j] - W[j*32+i];
    float d = (i == j) ? 1.0f : 0.0f;
    M[i][j] = d - xv;
    R[i][j] = d + xv;
  }
  __syncthreads();
  for (int k = 0; k < 32; ++k) {
    float inv = 1.0f / M[k][k];
    __syncthreads();
    if (t < 32) M[k][t] *= inv; else R[k][t-32] *= inv;
    __syncthreads();
    if (t < 32) fac[t] = M[t][k];
    __syncthreads();
    if (t < 32) {
      float mk = M[k][t];
      for (int i = 0; i < 32; ++i) {
        if (i == k) continue;
        M[i][t] -= fac[i] * mk;
      }
    } else {
      int tc = t - 32;
      float rk = R[k][tc];
      for (int i = 0; i < 32; ++i) {
        if (i == k) continue;
        R[i][tc] -= fac[i] * rk;
      }
    }
    __syncthreads();
  }
  // R = C^T ; store C row-major: C[p][q] = R[q][p]
  for (int idx = t; idx < 1024; idx += 64) {
    int p = idx >> 5, q = idx & 31;
    Cout[blockIdx.x * 1024 + idx] = R[q][p];
  }
}

// ---------------------------------------------------------------------------
// Kernel B: per-matrix sym eigendecomposition (parallel Jacobi, XOR pairing,
// blocked 2x2 update with bank-conflict-free pi-swap), then S = V log(w) V^T
// (zero diag), then q/k/v = offdiag(C S C^T) + q2/k2 norms.
// One 64-thread (single wave) block per matrix.
// pi-trick: lanes with odd row-pair-group parity swap both row and column
// roles (p<->q), which equals the same Givens update with s -> -s; this
// interleaves the LDS bank sets of the two lane groups -> <=2-way (free).
// ---------------------------------------------------------------------------
__global__ __launch_bounds__(64) void logm_qkv_kernel(
    const float* __restrict__ x, const float* __restrict__ Cm,
    float* __restrict__ qo, float* __restrict__ ko, float* __restrict__ vo,
    float* __restrict__ q2, float* __restrict__ k2) {
  __shared__ __align__(16) float buf0[32*SB];   // A -> Vrow -> C
  __shared__ __align__(16) float buf1[32*SB];   // Vt -> T (=offdiag S)
  __shared__ __align__(16) float buf2[32*SB];   // U
  __shared__ __align__(16) float2 cs[16];
  __shared__ __align__(16) float lw[32];
  const int t = threadIdx.x;
  const int m = blockIdx.x;
  const float* xm = x + (size_t)m * NF;

  // init A = x (stride SB, b128) and Vt = I
  #pragma unroll
  for (int s = 0; s < 4; ++s) {
    int fi = t + 64*s;               // float4 index 0..255
    int i = fi >> 3, j4 = (fi & 7) << 2;
    float4 xv = *(const float4*)&xm[(size_t)fi*4];
    *(float4*)&buf0[i*SB + j4] = xv;
    float4 iv;
    iv.x = (i == j4+0) ? 1.0f : 0.0f;
    iv.y = (i == j4+1) ? 1.0f : 0.0f;
    iv.z = (i == j4+2) ? 1.0f : 0.0f;
    iv.w = (i == j4+3) ? 1.0f : 0.0f;
    *(float4*)&buf1[i*SB + j4] = iv;
  }
  __syncthreads();

  const int ab = t >> 4;       // row-pair group 0..3
  const int bI = t & 15;       // col-pair index
  const int pi = ab & 1;       // role-swap parity

  for (int sw = 0; sw < NSWEEP; ++sw) {
    for (int r = 1; r < 32; ++r) {
      const int h = 31 - __builtin_clz((unsigned)r);
      const int lowmask = (1 << h) - 1;
      // phase 1: rotation angles for the 16 disjoint pairs {p, p^r}
      if (t < 16) {
        int p = ((t >> h) << (h+1)) | (t & lowmask);
        int q = p ^ r;
        float apq = buf0[p*SB+q];
        float c = 1.0f, s = 0.0f;
        if (fabsf(apq) > 1e-36f) {
          float app = buf0[p*SB+p];
          float aqq = buf0[q*SB+q];
          float tau = (aqq - app) / (2.0f * apq);
          float tt = 1.0f / (fabsf(tau) + sqrtf(1.0f + tau*tau));
          tt = (tau < 0.0f) ? -tt : tt;
          c = 1.0f / sqrtf(1.0f + tt*tt);
          s = tt * c;
        }
        cs[t] = make_float2(c, s);
      }
      __syncthreads();
      // phase 2: blocked A update, pi-swapped for bank spread.
      {
        int pb = ((bI >> h) << (h+1)) | (bI & lowmask);
        int qb = pb ^ r;
        if (pi) { int tmp = pb; pb = qb; qb = tmp; }
        const float2 cb2 = cs[bI];
        const float cbb = cb2.x;
        const float sbb = pi ? -cb2.y : cb2.y;
        #pragma unroll
        for (int u = 0; u < 4; ++u) {
          int a = ab + 4*u;
          int pa = ((a >> h) << (h+1)) | (a & lowmask);
          int qa = pa ^ r;
          if (pi) { int tmp = pa; pa = qa; qa = tmp; }
          float2 ca2 = cs[a];
          float caa = ca2.x;
          float saa = pi ? -ca2.y : ca2.y;
          float* rp = buf0 + pa*SB;
          float* rq = buf0 + qa*SB;
          float x11 = rp[pb], x12 = rp[qb];
          float x21 = rq[pb], x22 = rq[qb];
          // left rotation (rows, pair a)
          float y11 = caa*x11 - saa*x21;
          float y12 = caa*x12 - saa*x22;
          float y21 = fmaf(saa, x11, caa*x21);
          float y22 = fmaf(saa, x12, caa*x22);
          // right rotation (cols, pair b)
          rp[pb] = cbb*y11 - sbb*y12;
          rp[qb] = fmaf(sbb, y11, cbb*y12);
          rq[pb] = cbb*y21 - sbb*y22;
          rq[qb] = fmaf(sbb, y21, cbb*y22);
        }
        // V^T row rotations (V = V J  <=>  Vt = J^T Vt), float4 chunks
        #pragma unroll
        for (int vtk = 0; vtk < 2; ++vtk) {
          int tsk = t + 64*vtk;
          int pr = tsk >> 3;               // pair 0..15
          int ch = (tsk & 7) << 2;         // column chunk
          int p = ((pr >> h) << (h+1)) | (pr & lowmask);
          int q = p ^ r;
          float2 c2 = cs[pr];
          float4 vp = *(float4*)&buf1[p*SB + ch];
          float4 vq = *(float4*)&buf1[q*SB + ch];
          float4 np, nq;
          np.x = c2.x*vp.x - c2.y*vq.x;  nq.x = fmaf(c2.y, vp.x, c2.x*vq.x);
          np.y = c2.x*vp.y - c2.y*vq.y;  nq.y = fmaf(c2.y, vp.y, c2.x*vq.y);
          np.z = c2.x*vp.z - c2.y*vq.z;  nq.z = fmaf(c2.y, vp.z, c2.x*vq.z);
          np.w = c2.x*vp.w - c2.y*vq.w;  nq.w = fmaf(c2.y, vp.w, c2.x*vq.w);
          *(float4*)&buf1[p*SB + ch] = np;
          *(float4*)&buf1[q*SB + ch] = nq;
        }
      }
      __syncthreads();
    }
  }

  if (t < 32) lw[t] = logf(fmaxf(buf0[t*SB+t], 1e-30f));
  __syncthreads();
  // transpose Vt(buf1) -> Vrow(buf0): Vrow[i][k] = V[i][k] row-contiguous
  #pragma unroll
  for (int s = 0; s < 16; ++s) {
    int idx = t + 64*s;
    int i = idx >> 5, k = idx & 31;
    buf0[i*SB + k] = buf1[k*SB + i];
  }
  __syncthreads();

  const int rg = t >> 3, cg = t & 7;
  const int i0 = rg*4, j0 = cg*4;
  // T = offdiag(S), S[i][j] = sum_k (Vrow[i][k]*lw[k]) * Vrow[j][k]  -> buf1
  {
    float acc[4][4] = {};
    #pragma unroll
    for (int k4 = 0; k4 < 32; k4 += 4) {
      float4 lv = *(float4*)&lw[k4];
      float4 av[4], bv[4];
      #pragma unroll
      for (int d = 0; d < 4; ++d) {
        float4 a4 = *(float4*)&buf0[(i0+d)*SB + k4];
        av[d].x = a4.x*lv.x; av[d].y = a4.y*lv.y; av[d].z = a4.z*lv.z; av[d].w = a4.w*lv.w;
        bv[d] = *(float4*)&buf0[(j0+d)*SB + k4];
      }
      #pragma unroll
      for (int d = 0; d < 4; ++d)
        #pragma unroll
        for (int e = 0; e < 4; ++e) {
          acc[d][e] = fmaf(av[d].x, bv[e].x, acc[d][e]);
          acc[d][e] = fmaf(av[d].y, bv[e].y, acc[d][e]);
          acc[d][e] = fmaf(av[d].z, bv[e].z, acc[d][e]);
          acc[d][e] = fmaf(av[d].w, bv[e].w, acc[d][e]);
        }
    }
    #pragma unroll
    for (int d = 0; d < 4; ++d) {
      if (rg == cg) acc[d][d] = 0.0f;
      float4 z; z.x = acc[d][0]; z.y = acc[d][1]; z.z = acc[d][2]; z.w = acc[d][3];
      *(float4*)&buf1[(i0+d)*SB + j0] = z;
    }
  }
  __syncthreads();

  for (int w = 0; w < 3; ++w) {
    const float* Cw = Cm + w*1024;
    // load C -> buf0 (b128 both sides)
    #pragma unroll
    for (int s = 0; s < 4; ++s) {
      int fi = t + 64*s;
      int i = fi >> 3, c4 = (fi & 7) << 2;
      *(float4*)&buf0[i*SB + c4] = *(const float4*)&Cw[fi*4];
    }
    __syncthreads();
    // U = C * T (T symmetric): U[i][j] = sum_k C[i][k] * T[j][k] -> buf2
    {
      float acc[4][4] = {};
      #pragma unroll
      for (int k4 = 0; k4 < 32; k4 += 4) {
        float4 av[4], bv[4];
        #pragma unroll
        for (int d = 0; d < 4; ++d) {
          av[d] = *(float4*)&buf0[(i0+d)*SB + k4];
          bv[d] = *(float4*)&buf1[(j0+d)*SB + k4];
        }
        #pragma unroll
        for (int d = 0; d < 4; ++d)
          #pragma unroll
          for (int e = 0; e < 4; ++e) {
            acc[d][e] = fmaf(av[d].x, bv[e].x, acc[d][e]);
            acc[d][e] = fmaf(av[d].y, bv[e].y, acc[d][e]);
            acc[d][e] = fmaf(av[d].z, bv[e].z, acc[d][e]);
            acc[d][e] = fmaf(av[d].w, bv[e].w, acc[d][e]);
          }
      }
      #pragma unroll
      for (int d = 0; d < 4; ++d) {
        float4 z; z.x = acc[d][0]; z.y = acc[d][1]; z.z = acc[d][2]; z.w = acc[d][3];
        *(float4*)&buf2[(i0+d)*SB + j0] = z;
      }
    }
    __syncthreads();
    // Z = U * C^T: Z[i][j] = sum_k U[i][k] * C[j][k]; offdiag -> global
    {
      float acc[4][4] = {};
      #pragma unroll
      for (int k4 = 0; k4 < 32; k4 += 4) {
        float4 av[4], bv[4];
        #pragma unroll
        for (int d = 0; d < 4; ++d) {
          av[d] = *(float4*)&buf2[(i0+d)*SB + k4];
          bv[d] = *(float4*)&buf0[(j0+d)*SB + k4];
        }
        #pragma unroll
        for (int d = 0; d < 4; ++d)
          #pragma unroll
          for (int e = 0; e < 4; ++e) {
            acc[d][e] = fmaf(av[d].x, bv[e].x, acc[d][e]);
            acc[d][e] = fmaf(av[d].y, bv[e].y, acc[d][e]);
            acc[d][e] = fmaf(av[d].z, bv[e].z, acc[d][e]);
            acc[d][e] = fmaf(av[d].w, bv[e].w, acc[d][e]);
          }
      }
      float ss = 0.0f;
      float* outp = (w == 0) ? qo : ((w == 1) ? ko : vo);
      #pragma unroll
      for (int d = 0; d < 4; ++d) {
        if (rg == cg) acc[d][d] = 0.0f;
        ss = fmaf(acc[d][0], acc[d][0], ss);
        ss = fmaf(acc[d][1], acc[d][1], ss);
        ss = fmaf(acc[d][2], acc[d][2], ss);
        ss = fmaf(acc[d][3], acc[d][3], ss);
        float4 z; z.x = acc[d][0]; z.y = acc[d][1]; z.z = acc[d][2]; z.w = acc[d][3];
        *(float4*)&outp[(size_t)m*NF + (i0+d)*32 + j0] = z;
      }
      if (w < 2) {
        #pragma unroll
        for (int off = 32; off > 0; off >>= 1)
          ss += __shfl_down(ss, off);
        if (t == 0) ((w == 0) ? q2 : k2)[m] = ss;
      }
    }
    __syncthreads();
  }
}

// ---------------------------------------------------------------------------
// Kernel C1: G[b,j,i] = <kf[b,j], qf[b,i]> (K=1024), fused scores epilogue.
// ---------------------------------------------------------------------------
__global__ __launch_bounds__(256) void scores_kernel(
    const float* __restrict__ qf, const float* __restrict__ kf,
    const float* __restrict__ q2, const float* __restrict__ k2,
    float* __restrict__ P) {
  __shared__ float Ks[64][17];
  __shared__ float Qs[64][17];
  const int b = blockIdx.z;
  const int j0 = blockIdx.y * 64;
  const int i0 = blockIdx.x * 64;
  const int tx = threadIdx.x & 15, ty = threadIdx.x >> 4;
  const int lrow = threadIdx.x >> 2;
  const int lc4 = (threadIdx.x & 3) * 4;
  float acc[4][4] = {};
  const float* kb = kf + (size_t)(b*NSQ + j0) * NF;
  const float* qb = qf + (size_t)(b*NSQ + i0) * NF;
  for (int f0 = 0; f0 < NF; f0 += 16) {
    float4 kv = *(const float4*)(kb + (size_t)lrow*NF + f0 + lc4);
    float4 qv = *(const float4*)(qb + (size_t)lrow*NF + f0 + lc4);
    Ks[lrow][lc4+0] = kv.x; Ks[lrow][lc4+1] = kv.y; Ks[lrow][lc4+2] = kv.z; Ks[lrow][lc4+3] = kv.w;
    Qs[lrow][lc4+0] = qv.x; Qs[lrow][lc4+1] = qv.y; Qs[lrow][lc4+2] = qv.z; Qs[lrow][lc4+3] = qv.w;
    __syncthreads();
    #pragma unroll
    for (int kk = 0; kk < 16; ++kk) {
      float a0 = Ks[ty*4+0][kk], a1 = Ks[ty*4+1][kk], a2 = Ks[ty*4+2][kk], a3 = Ks[ty*4+3][kk];
      float b0 = Qs[tx*4+0][kk], b1 = Qs[tx*4+1][kk], b2 = Qs[tx*4+2][kk], b3 = Qs[tx*4+3][kk];
      acc[0][0]=fmaf(a0,b0,acc[0][0]); acc[0][1]=fmaf(a0,b1,acc[0][1]);
      acc[0][2]=fmaf(a0,b2,acc[0][2]); acc[0][3]=fmaf(a0,b3,acc[0][3]);
      acc[1][0]=fmaf(a1,b0,acc[1][0]); acc[1][1]=fmaf(a1,b1,acc[1][1]);
      acc[1][2]=fmaf(a1,b2,acc[1][2]); acc[1][3]=fmaf(a1,b3,acc[1][3]);
      acc[2][0]=fmaf(a2,b0,acc[2][0]); acc[2][1]=fmaf(a2,b1,acc[2][1]);
      acc[2][2]=fmaf(a2,b2,acc[2][2]); acc[2][3]=fmaf(a2,b3,acc[2][3]);
      acc[3][0]=fmaf(a3,b0,acc[3][0]); acc[3][1]=fmaf(a3,b1,acc[3][1]);
      acc[3][2]=fmaf(a3,b2,acc[3][2]); acc[3][3]=fmaf(a3,b3,acc[3][3]);
    }
    __syncthreads();
  }
  #pragma unroll
  for (int u = 0; u < 4; ++u) {
    int j = j0 + ty*4 + u;
    float kj = k2[b*NSQ + j];
    #pragma unroll
    for (int vv = 0; vv < 4; ++vv) {
      int i = i0 + tx*4 + vv;
      float d2 = kj + q2[b*NSQ + i] - 2.0f * acc[u][vv];
      float e = sqrtf(fmaxf(d2, 1e-12f));
      float sc = 1.0f / (1.0f + log1pf(e));
      P[(size_t)(b*NSQ + j)*NSQ + i] = sc;
    }
  }
}

// ---------------------------------------------------------------------------
// Kernel C1b: softmax over j (axis -2) for each (b,i) column, in place.
// ---------------------------------------------------------------------------
__global__ __launch_bounds__(256) void softmax_kernel(float* __restrict__ P) {
  __shared__ float red[4][64];
  const int b = blockIdx.x >> 3;
  const int i0 = (blockIdx.x & 7) * 64;
  const int il = threadIdx.x & 63;
  const int jg = threadIdx.x >> 6;   // 0..3
  float* base = P + (size_t)b*NSQ*NSQ + i0 + il;
  float mx = -1e30f;
  for (int j = jg*128; j < jg*128 + 128; ++j)
    mx = fmaxf(mx, base[(size_t)j*NSQ]);
  red[jg][il] = mx;
  __syncthreads();
  float cm = fmaxf(fmaxf(red[0][il], red[1][il]), fmaxf(red[2][il], red[3][il]));
  float ssum = 0.0f;
  for (int j = jg*128; j < jg*128 + 128; ++j)
    ssum += expf(base[(size_t)j*NSQ] - cm);
  __syncthreads();
  red[jg][il] = ssum;
  __syncthreads();
  float inv = 1.0f / (red[0][il] + red[1][il] + red[2][il] + red[3][il]);
  for (int j = jg*128; j < jg*128 + 128; ++j) {
    size_t o = (size_t)j*NSQ;
    base[o] = expf(base[o] - cm) * inv;
  }
}

// ---------------------------------------------------------------------------
// Kernel C2: out[b,c,f] = sum_a P[b,c,a] * vf[b,a,f]   (NN GEMM, K=512)
// ---------------------------------------------------------------------------
__global__ __launch_bounds__(256) void out_gemm_kernel(
    const float* __restrict__ P, const float* __restrict__ vf,
    float* __restrict__ out) {
  __shared__ float Ps[64][17];
  __shared__ float Vs[16][68];
  const int b = blockIdx.z;
  const int c0 = blockIdx.y * 64;
  const int f0 = blockIdx.x * 64;
  const int tx = threadIdx.x & 15, ty = threadIdx.x >> 4;
  float acc[4][4] = {};
  const float* Pb = P + (size_t)b * NSQ * NSQ;
  const float* Vb = vf + (size_t)b * NSQ * NF;
  for (int a0 = 0; a0 < NSQ; a0 += 16) {
    {
      int row = threadIdx.x >> 2;
      int c4 = (threadIdx.x & 3) * 4;
      float4 pv = *(const float4*)(Pb + (size_t)(c0 + row) * NSQ + a0 + c4);
      Ps[row][c4+0]=pv.x; Ps[row][c4+1]=pv.y; Ps[row][c4+2]=pv.z; Ps[row][c4+3]=pv.w;
    }
    {
      int row = threadIdx.x >> 4;
      int c4 = (threadIdx.x & 15) * 4;
      float4 vv4 = *(const float4*)(Vb + (size_t)(a0 + row) * NF + f0 + c4);
      Vs[row][c4+0]=vv4.x; Vs[row][c4+1]=vv4.y; Vs[row][c4+2]=vv4.z; Vs[row][c4+3]=vv4.w;
    }
    __syncthreads();
    #pragma unroll
    for (int kk = 0; kk < 16; ++kk) {
      float a0r = Ps[ty*4+0][kk], a1r = Ps[ty*4+1][kk], a2r = Ps[ty*4+2][kk], a3r = Ps[ty*4+3][kk];
      float b0 = Vs[kk][tx*4+0], b1 = Vs[kk][tx*4+1], b2 = Vs[kk][tx*4+2], b3 = Vs[kk][tx*4+3];
      acc[0][0]=fmaf(a0r,b0,acc[0][0]); acc[0][1]=fmaf(a0r,b1,acc[0][1]);
      acc[0][2]=fmaf(a0r,b2,acc[0][2]); acc[0][3]=fmaf(a0r,b3,acc[0][3]);
      acc[1][0]=fmaf(a1r,b0,acc[1][0]); acc[1][1]=fmaf(a1r,b1,acc[1][1]);
      acc[1][2]=fmaf(a1r,b2,acc[1][2]); acc[1][3]=fmaf(a1r,b3,acc[1][3]);
      acc[2][0]=fmaf(a2r,b0,acc[2][0]); acc[2][1]=fmaf(a2r,b1,acc[2][1]);
      acc[2][2]=fmaf(a2r,b2,acc[2][2]); acc[2][3]=fmaf(a2r,b3,acc[2][3]);
      acc[3][0]=fmaf(a3r,b0,acc[3][0]); acc[3][1]=fmaf(a3r,b1,acc[3][1]);
      acc[3][2]=fmaf(a3r,b2,acc[3][2]); acc[3][3]=fmaf(a3r,b3,acc[3][3]);
    }
    __syncthreads();
  }
  #pragma unroll
  for (int u = 0; u < 4; ++u) {
    float4 o;
    o.x = acc[u][0]; o.y = acc[u][1]; o.z = acc[u][2]; o.w = acc[u][3];
    *(float4*)(out + (size_t)(b*NSQ + c0 + ty*4 + u) * NF + f0 + tx*4) = o;
  }
}

extern "C" void kernel_launch(void* const* d_in, const int* in_sizes, int n_in,
                              void* d_out, int out_size, void* d_ws, size_t ws_size,
                              hipStream_t stream) {
  const float* x  = (const float*)d_in[0];
  const float* qw = (const float*)d_in[1];
  const float* kw = (const float*)d_in[2];
  const float* vw = (const float*)d_in[3];
  float* ws = (float*)d_ws;
  float* C  = ws;
  float* q  = ws + 3072;
  float* k  = q + (size_t)NMAT * NF;
  float* v  = k + (size_t)NMAT * NF;
  float* q2 = v + (size_t)NMAT * NF;
  float* k2 = q2 + NMAT;
  float* P  = k2 + NMAT;
  float* out = (float*)d_out;

  cayley_kernel<<<dim3(3), dim3(64), 0, stream>>>(qw, kw, vw, C);
  logm_qkv_kernel<<<dim3(NMAT), dim3(64), 0, stream>>>(x, C, q, k, v, q2, k2);
  scores_kernel<<<dim3(8, 8, NB), dim3(256), 0, stream>>>(q, k, q2, k2, P);
  softmax_kernel<<<dim3(NB * 8), dim3(256), 0, stream>>>(P);
  out_gemm_kernel<<<dim3(16, 8, NB), dim3(256), 0, stream>>>(P, v, out);
}

// Round 7
// 1532.950 us; speedup vs baseline: 1.6906x; 1.0114x over previous
//
#include <hip/hip_runtime.h>
#include <math.h>

#define NB 16
#define NSQ 512
#define NMAT (NB*NSQ)   // 8192
#define NF 1024         // 32*32
#define NSWEEP 7        // 6 sweeps FAILS (absmax 0.195); 7 hits the comparison floor.
#define SB 36           // LDS row stride (floats): 144B = multiple of 16 -> b128-aligned rows

// ---------------------------------------------------------------------------
// Kernel A: Cayley maps. C = (I - X)(I + X)^{-1}, X = W - W^T.
// ---------------------------------------------------------------------------
__global__ __launch_bounds__(64) void cayley_kernel(
    const float* __restrict__ qw, const float* __restrict__ kw,
    const float* __restrict__ vw, float* __restrict__ Cout) {
  __shared__ float M[32][33];
  __shared__ float R[32][33];
  __shared__ float fac[32];
  const float* W = (blockIdx.x == 0) ? qw : ((blockIdx.x == 1) ? kw : vw);
  const int t = threadIdx.x;
  for (int idx = t; idx < 1024; idx += 64) {
    int i = idx >> 5, j = idx & 31;
    float xv = W[i*32+j] - W[j*32+i];
    float d = (i == j) ? 1.0f : 0.0f;
    M[i][j] = d - xv;
    R[i][j] = d + xv;
  }
  __syncthreads();
  for (int k = 0; k < 32; ++k) {
    float inv = 1.0f / M[k][k];
    __syncthreads();
    if (t < 32) M[k][t] *= inv; else R[k][t-32] *= inv;
    __syncthreads();
    if (t < 32) fac[t] = M[t][k];
    __syncthreads();
    if (t < 32) {
      float mk = M[k][t];
      for (int i = 0; i < 32; ++i) {
        if (i == k) continue;
        M[i][t] -= fac[i] * mk;
      }
    } else {
      int tc = t - 32;
      float rk = R[k][tc];
      for (int i = 0; i < 32; ++i) {
        if (i == k) continue;
        R[i][tc] -= fac[i] * rk;
      }
    }
    __syncthreads();
  }
  // R = C^T ; store C row-major: C[p][q] = R[q][p]
  for (int idx = t; idx < 1024; idx += 64) {
    int p = idx >> 5, q = idx & 31;
    Cout[blockIdx.x * 1024 + idx] = R[q][p];
  }
}

// ---------------------------------------------------------------------------
// Kernel B: per-matrix sym eigendecomposition (parallel Jacobi, XOR pairing),
// then S = V log(w) V^T (zero diag), then q/k/v = offdiag(C S C^T) + norms.
// One 64-thread (single wave) block per matrix.
// A-update: BISECT ROUND — two-phase b128 scheme at r==1 ONLY; scalar
// pi-swap 2x2 blocks for all r>=2 (the known-good R3 path).
// [History: fused-chunk r<=3 (R4/R5) and two-phase r<=3 (R6) both FAILED
//  (absmax 0.18 / 0.056) despite symbolic equivalence to the scalar path;
//  this round isolates whether the two-phase structure itself is sound.]
// ---------------------------------------------------------------------------
__global__ __launch_bounds__(64) void logm_qkv_kernel(
    const float* __restrict__ x, const float* __restrict__ Cm,
    float* __restrict__ qo, float* __restrict__ ko, float* __restrict__ vo,
    float* __restrict__ q2, float* __restrict__ k2) {
  __shared__ __align__(16) float buf0[32*SB];   // A -> Vrow -> C
  __shared__ __align__(16) float buf1[32*SB];   // Vt -> T (=offdiag S)
  __shared__ __align__(16) float buf2[32*SB];   // U
  __shared__ __align__(16) float2 cs[16];
  __shared__ __align__(16) float lw[32];
  const int t = threadIdx.x;
  const int m = blockIdx.x;
  const float* xm = x + (size_t)m * NF;

  // init A = x (stride SB, b128) and Vt = I
  #pragma unroll
  for (int s = 0; s < 4; ++s) {
    int fi = t + 64*s;               // float4 index 0..255
    int i = fi >> 3, j4 = (fi & 7) << 2;
    float4 xv = *(const float4*)&xm[(size_t)fi*4];
    *(float4*)&buf0[i*SB + j4] = xv;
    float4 iv;
    iv.x = (i == j4+0) ? 1.0f : 0.0f;
    iv.y = (i == j4+1) ? 1.0f : 0.0f;
    iv.z = (i == j4+2) ? 1.0f : 0.0f;
    iv.w = (i == j4+3) ? 1.0f : 0.0f;
    *(float4*)&buf1[i*SB + j4] = iv;
  }
  __syncthreads();

  const int ab = t >> 4;       // row-pair group 0..3
  const int bI = t & 15;       // col-pair index
  const int pi = ab & 1;       // role-swap parity

  for (int sw = 0; sw < NSWEEP; ++sw) {
    for (int r = 1; r < 32; ++r) {
      const int h = 31 - __builtin_clz((unsigned)r);
      const int lowmask = (1 << h) - 1;
      // phase 1: rotation angles for the 16 disjoint pairs {p, p^r}
      if (t < 16) {
        int p = ((t >> h) << (h+1)) | (t & lowmask);
        int q = p ^ r;
        float apq = buf0[p*SB+q];
        float c = 1.0f, s = 0.0f;
        if (fabsf(apq) > 1e-36f) {
          float app = buf0[p*SB+p];
          float aqq = buf0[q*SB+q];
          float tau = (aqq - app) / (2.0f * apq);
          float tt = 1.0f / (fabsf(tau) + sqrtf(1.0f + tau*tau));
          tt = (tau < 0.0f) ? -tt : tt;
          c = 1.0f / sqrtf(1.0f + tt*tt);
          s = tt * c;
        }
        cs[t] = make_float2(c, s);
      }
      __syncthreads();
      if (r == 1) {
        // --- phase A: row rotations B = J^T A (b128); pairs (2k,2k+1) ---
        #pragma unroll
        for (int vtk = 0; vtk < 2; ++vtk) {
          int tsk = t + 64*vtk;
          int pr = tsk >> 3;               // pair 0..15
          int ch = (tsk & 7) << 2;         // column chunk
          int p = pr << 1;                 // h=0 -> p = 2*pr
          int q = p | 1;
          float2 c2 = cs[pr];
          float4 ap = *(float4*)&buf0[p*SB + ch];
          float4 aq = *(float4*)&buf0[q*SB + ch];
          float4 np, nq;
          np.x = c2.x*ap.x - c2.y*aq.x;  nq.x = fmaf(c2.y, ap.x, c2.x*aq.x);
          np.y = c2.x*ap.y - c2.y*aq.y;  nq.y = fmaf(c2.y, ap.y, c2.x*aq.y);
          np.z = c2.x*ap.z - c2.y*aq.z;  nq.z = fmaf(c2.y, ap.z, c2.x*aq.z);
          np.w = c2.x*ap.w - c2.y*aq.w;  nq.w = fmaf(c2.y, ap.w, c2.x*aq.w);
          *(float4*)&buf0[p*SB + ch] = np;
          *(float4*)&buf0[q*SB + ch] = nq;
        }
        __syncthreads();   // r is loop-uniform -> all threads reach this
        // --- phase B: col rotations A' = B J, in-register per row-chunk;
        //     local col pairs (0,1) w/ cs[2c] and (2,3) w/ cs[2c+1] ---
        #pragma unroll
        for (int s4 = 0; s4 < 4; ++s4) {
          int tsk = t + 64*s4;             // 0..255
          int i = tsk >> 3;                // row 0..31
          int cch = tsk & 7;               // chunk 0..7 (cols 4c..4c+3)
          float2 cA = cs[2*cch];
          float2 cB = cs[2*cch+1];
          float4 y = *(float4*)&buf0[i*SB + 4*cch];
          float4 z;
          z.x = cA.x*y.x - cA.y*y.y;  z.y = fmaf(cA.y, y.x, cA.x*y.y);
          z.z = cB.x*y.z - cB.y*y.w;  z.w = fmaf(cB.y, y.z, cB.x*y.w);
          *(float4*)&buf0[i*SB + 4*cch] = z;
        }
      } else {
        // blocked 2x2 scalar update, pi-swapped for bank spread (known-good).
        int pb = ((bI >> h) << (h+1)) | (bI & lowmask);
        int qb = pb ^ r;
        if (pi) { int tmp = pb; pb = qb; qb = tmp; }
        const float2 cb2 = cs[bI];
        const float cbb = cb2.x;
        const float sbb = pi ? -cb2.y : cb2.y;
        #pragma unroll
        for (int u = 0; u < 4; ++u) {
          int a = ab + 4*u;
          int pa = ((a >> h) << (h+1)) | (a & lowmask);
          int qa = pa ^ r;
          if (pi) { int tmp = pa; pa = qa; qa = tmp; }
          float2 ca2 = cs[a];
          float caa = ca2.x;
          float saa = pi ? -ca2.y : ca2.y;
          float* rp = buf0 + pa*SB;
          float* rq = buf0 + qa*SB;
          float x11 = rp[pb], x12 = rp[qb];
          float x21 = rq[pb], x22 = rq[qb];
          float y11 = caa*x11 - saa*x21;
          float y12 = caa*x12 - saa*x22;
          float y21 = fmaf(saa, x11, caa*x21);
          float y22 = fmaf(saa, x12, caa*x22);
          rp[pb] = cbb*y11 - sbb*y12;
          rp[qb] = fmaf(sbb, y11, cbb*y12);
          rq[pb] = cbb*y21 - sbb*y22;
          rq[qb] = fmaf(sbb, y21, cbb*y22);
        }
      }
      // V^T row rotations (V = V J  <=>  Vt = J^T Vt), float4 chunks
      #pragma unroll
      for (int vtk = 0; vtk < 2; ++vtk) {
        int tsk = t + 64*vtk;
        int pr = tsk >> 3;               // pair 0..15
        int ch = (tsk & 7) << 2;         // column chunk
        int p = ((pr >> h) << (h+1)) | (pr & lowmask);
        int q = p ^ r;
        float2 c2 = cs[pr];
        float4 vp = *(float4*)&buf1[p*SB + ch];
        float4 vq = *(float4*)&buf1[q*SB + ch];
        float4 np, nq;
        np.x = c2.x*vp.x - c2.y*vq.x;  nq.x = fmaf(c2.y, vp.x, c2.x*vq.x);
        np.y = c2.x*vp.y - c2.y*vq.y;  nq.y = fmaf(c2.y, vp.y, c2.x*vq.y);
        np.z = c2.x*vp.z - c2.y*vq.z;  nq.z = fmaf(c2.y, vp.z, c2.x*vq.z);
        np.w = c2.x*vp.w - c2.y*vq.w;  nq.w = fmaf(c2.y, vp.w, c2.x*vq.w);
        *(float4*)&buf1[p*SB + ch] = np;
        *(float4*)&buf1[q*SB + ch] = nq;
      }
      __syncthreads();
    }
  }

  if (t < 32) lw[t] = logf(fmaxf(buf0[t*SB+t], 1e-30f));
  __syncthreads();
  // transpose Vt(buf1) -> Vrow(buf0): Vrow[i][k] = V[i][k] row-contiguous
  #pragma unroll
  for (int s = 0; s < 16; ++s) {
    int idx = t + 64*s;
    int i = idx >> 5, k = idx & 31;
    buf0[i*SB + k] = buf1[k*SB + i];
  }
  __syncthreads();

  const int rg = t >> 3, cg = t & 7;
  const int i0 = rg*4, j0 = cg*4;
  // T = offdiag(S), S[i][j] = sum_k (Vrow[i][k]*lw[k]) * Vrow[j][k]  -> buf1
  {
    float acc[4][4] = {};
    #pragma unroll
    for (int k4 = 0; k4 < 32; k4 += 4) {
      float4 lv = *(float4*)&lw[k4];
      float4 av[4], bv[4];
      #pragma unroll
      for (int d = 0; d < 4; ++d) {
        float4 a4 = *(float4*)&buf0[(i0+d)*SB + k4];
        av[d].x = a4.x*lv.x; av[d].y = a4.y*lv.y; av[d].z = a4.z*lv.z; av[d].w = a4.w*lv.w;
        bv[d] = *(float4*)&buf0[(j0+d)*SB + k4];
      }
      #pragma unroll
      for (int d = 0; d < 4; ++d)
        #pragma unroll
        for (int e = 0; e < 4; ++e) {
          acc[d][e] = fmaf(av[d].x, bv[e].x, acc[d][e]);
          acc[d][e] = fmaf(av[d].y, bv[e].y, acc[d][e]);
          acc[d][e] = fmaf(av[d].z, bv[e].z, acc[d][e]);
          acc[d][e] = fmaf(av[d].w, bv[e].w, acc[d][e]);
        }
    }
    #pragma unroll
    for (int d = 0; d < 4; ++d) {
      if (rg == cg) acc[d][d] = 0.0f;
      float4 z; z.x = acc[d][0]; z.y = acc[d][1]; z.z = acc[d][2]; z.w = acc[d][3];
      *(float4*)&buf1[(i0+d)*SB + j0] = z;
    }
  }
  __syncthreads();

  for (int w = 0; w < 3; ++w) {
    const float* Cw = Cm + w*1024;
    // load C -> buf0 (b128 both sides)
    #pragma unroll
    for (int s = 0; s < 4; ++s) {
      int fi = t + 64*s;
      int i = fi >> 3, c4 = (fi & 7) << 2;
      *(float4*)&buf0[i*SB + c4] = *(const float4*)&Cw[fi*4];
    }
    __syncthreads();
    // U = C * T (T symmetric): U[i][j] = sum_k C[i][k] * T[j][k] -> buf2
    {
      float acc[4][4] = {};
      #pragma unroll
      for (int k4 = 0; k4 < 32; k4 += 4) {
        float4 av[4], bv[4];
        #pragma unroll
        for (int d = 0; d < 4; ++d) {
          av[d] = *(float4*)&buf0[(i0+d)*SB + k4];
          bv[d] = *(float4*)&buf1[(j0+d)*SB + k4];
        }
        #pragma unroll
        for (int d = 0; d < 4; ++d)
          #pragma unroll
          for (int e = 0; e < 4; ++e) {
            acc[d][e] = fmaf(av[d].x, bv[e].x, acc[d][e]);
            acc[d][e] = fmaf(av[d].y, bv[e].y, acc[d][e]);
            acc[d][e] = fmaf(av[d].z, bv[e].z, acc[d][e]);
            acc[d][e] = fmaf(av[d].w, bv[e].w, acc[d][e]);
          }
      }
      #pragma unroll
      for (int d = 0; d < 4; ++d) {
        float4 z; z.x = acc[d][0]; z.y = acc[d][1]; z.z = acc[d][2]; z.w = acc[d][3];
        *(float4*)&buf2[(i0+d)*SB + j0] = z;
      }
    }
    __syncthreads();
    // Z = U * C^T: Z[i][j] = sum_k U[i][k] * C[j][k]; offdiag -> global
    {
      float acc[4][4] = {};
      #pragma unroll
      for (int k4 = 0; k4 < 32; k4 += 4) {
        float4 av[4], bv[4];
        #pragma unroll
        for (int d = 0; d < 4; ++d) {
          av[d] = *(float4*)&buf2[(i0+d)*SB + k4];
          bv[d] = *(float4*)&buf0[(j0+d)*SB + k4];
        }
        #pragma unroll
        for (int d = 0; d < 4; ++d)
          #pragma unroll
          for (int e = 0; e < 4; ++e) {
            acc[d][e] = fmaf(av[d].x, bv[e].x, acc[d][e]);
            acc[d][e] = fmaf(av[d].y, bv[e].y, acc[d][e]);
            acc[d][e] = fmaf(av[d].z, bv[e].z, acc[d][e]);
            acc[d][e] = fmaf(av[d].w, bv[e].w, acc[d][e]);
          }
      }
      float ss = 0.0f;
      float* outp = (w == 0) ? qo : ((w == 1) ? ko : vo);
      #pragma unroll
      for (int d = 0; d < 4; ++d) {
        if (rg == cg) acc[d][d] = 0.0f;
        ss = fmaf(acc[d][0], acc[d][0], ss);
        ss = fmaf(acc[d][1], acc[d][1], ss);
        ss = fmaf(acc[d][2], acc[d][2], ss);
        ss = fmaf(acc[d][3], acc[d][3], ss);
        float4 z; z.x = acc[d][0]; z.y = acc[d][1]; z.z = acc[d][2]; z.w = acc[d][3];
        *(float4*)&outp[(size_t)m*NF + (i0+d)*32 + j0] = z;
      }
      if (w < 2) {
        #pragma unroll
        for (int off = 32; off > 0; off >>= 1)
          ss += __shfl_down(ss, off);
        if (t == 0) ((w == 0) ? q2 : k2)[m] = ss;
      }
    }
    __syncthreads();
  }
}

// ---------------------------------------------------------------------------
// Kernel C1: G[b,j,i] = <kf[b,j], qf[b,i]> (K=1024), fused scores epilogue.
// ---------------------------------------------------------------------------
__global__ __launch_bounds__(256) void scores_kernel(
    const float* __restrict__ qf, const float* __restrict__ kf,
    const float* __restrict__ q2, const float* __restrict__ k2,
    float* __restrict__ P) {
  __shared__ float Ks[64][17];
  __shared__ float Qs[64][17];
  const int b = blockIdx.z;
  const int j0 = blockIdx.y * 64;
  const int i0 = blockIdx.x * 64;
  const int tx = threadIdx.x & 15, ty = threadIdx.x >> 4;
  const int lrow = threadIdx.x >> 2;
  const int lc4 = (threadIdx.x & 3) * 4;
  float acc[4][4] = {};
  const float* kb = kf + (size_t)(b*NSQ + j0) * NF;
  const float* qb = qf + (size_t)(b*NSQ + i0) * NF;
  for (int f0 = 0; f0 < NF; f0 += 16) {
    float4 kv = *(const float4*)(kb + (size_t)lrow*NF + f0 + lc4);
    float4 qv = *(const float4*)(qb + (size_t)lrow*NF + f0 + lc4);
    Ks[lrow][lc4+0] = kv.x; Ks[lrow][lc4+1] = kv.y; Ks[lrow][lc4+2] = kv.z; Ks[lrow][lc4+3] = kv.w;
    Qs[lrow][lc4+0] = qv.x; Qs[lrow][lc4+1] = qv.y; Qs[lrow][lc4+2] = qv.z; Qs[lrow][lc4+3] = qv.w;
    __syncthreads();
    #pragma unroll
    for (int kk = 0; kk < 16; ++kk) {
      float a0 = Ks[ty*4+0][kk], a1 = Ks[ty*4+1][kk], a2 = Ks[ty*4+2][kk], a3 = Ks[ty*4+3][kk];
      float b0 = Qs[tx*4+0][kk], b1 = Qs[tx*4+1][kk], b2 = Qs[tx*4+2][kk], b3 = Qs[tx*4+3][kk];
      acc[0][0]=fmaf(a0,b0,acc[0][0]); acc[0][1]=fmaf(a0,b1,acc[0][1]);
      acc[0][2]=fmaf(a0,b2,acc[0][2]); acc[0][3]=fmaf(a0,b3,acc[0][3]);
      acc[1][0]=fmaf(a1,b0,acc[1][0]); acc[1][1]=fmaf(a1,b1,acc[1][1]);
      acc[1][2]=fmaf(a1,b2,acc[1][2]); acc[1][3]=fmaf(a1,b3,acc[1][3]);
      acc[2][0]=fmaf(a2,b0,acc[2][0]); acc[2][1]=fmaf(a2,b1,acc[2][1]);
      acc[2][2]=fmaf(a2,b2,acc[2][2]); acc[2][3]=fmaf(a2,b3,acc[2][3]);
      acc[3][0]=fmaf(a3,b0,acc[3][0]); acc[3][1]=fmaf(a3,b1,acc[3][1]);
      acc[3][2]=fmaf(a3,b2,acc[3][2]); acc[3][3]=fmaf(a3,b3,acc[3][3]);
    }
    __syncthreads();
  }
  #pragma unroll
  for (int u = 0; u < 4; ++u) {
    int j = j0 + ty*4 + u;
    float kj = k2[b*NSQ + j];
    #pragma unroll
    for (int vv = 0; vv < 4; ++vv) {
      int i = i0 + tx*4 + vv;
      float d2 = kj + q2[b*NSQ + i] - 2.0f * acc[u][vv];
      float e = sqrtf(fmaxf(d2, 1e-12f));
      float sc = 1.0f / (1.0f + log1pf(e));
      P[(size_t)(b*NSQ + j)*NSQ + i] = sc;
    }
  }
}

// ---------------------------------------------------------------------------
// Kernel C1b: softmax over j (axis -2) for each (b,i) column, in place.
// ---------------------------------------------------------------------------
__global__ __launch_bounds__(256) void softmax_kernel(float* __restrict__ P) {
  __shared__ float red[4][64];
  const int b = blockIdx.x >> 3;
  const int i0 = (blockIdx.x & 7) * 64;
  const int il = threadIdx.x & 63;
  const int jg = threadIdx.x >> 6;   // 0..3
  float* base = P + (size_t)b*NSQ*NSQ + i0 + il;
  float mx = -1e30f;
  for (int j = jg*128; j < jg*128 + 128; ++j)
    mx = fmaxf(mx, base[(size_t)j*NSQ]);
  red[jg][il] = mx;
  __syncthreads();
  float cm = fmaxf(fmaxf(red[0][il], red[1][il]), fmaxf(red[2][il], red[3][il]));
  float ssum = 0.0f;
  for (int j = jg*128; j < jg*128 + 128; ++j)
    ssum += expf(base[(size_t)j*NSQ] - cm);
  __syncthreads();
  red[jg][il] = ssum;
  __syncthreads();
  float inv = 1.0f / (red[0][il] + red[1][il] + red[2][il] + red[3][il]);
  for (int j = jg*128; j < jg*128 + 128; ++j) {
    size_t o = (size_t)j*NSQ;
    base[o] = expf(base[o] - cm) * inv;
  }
}

// ---------------------------------------------------------------------------
// Kernel C2: out[b,c,f] = sum_a P[b,c,a] * vf[b,a,f]   (NN GEMM, K=512)
// ---------------------------------------------------------------------------
__global__ __launch_bounds__(256) void out_gemm_kernel(
    const float* __restrict__ P, const float* __restrict__ vf,
    float* __restrict__ out) {
  __shared__ float Ps[64][17];
  __shared__ float Vs[16][68];
  const int b = blockIdx.z;
  const int c0 = blockIdx.y * 64;
  const int f0 = blockIdx.x * 64;
  const int tx = threadIdx.x & 15, ty = threadIdx.x >> 4;
  float acc[4][4] = {};
  const float* Pb = P + (size_t)b * NSQ * NSQ;
  const float* Vb = vf + (size_t)b * NSQ * NF;
  for (int a0 = 0; a0 < NSQ; a0 += 16) {
    {
      int row = threadIdx.x >> 2;
      int c4 = (threadIdx.x & 3) * 4;
      float4 pv = *(const float4*)(Pb + (size_t)(c0 + row) * NSQ + a0 + c4);
      Ps[row][c4+0]=pv.x; Ps[row][c4+1]=pv.y; Ps[row][c4+2]=pv.z; Ps[row][c4+3]=pv.w;
    }
    {
      int row = threadIdx.x >> 4;
      int c4 = (threadIdx.x & 15) * 4;
      float4 vv4 = *(const float4*)(Vb + (size_t)(a0 + row) * NF + f0 + c4);
      Vs[row][c4+0]=vv4.x; Vs[row][c4+1]=vv4.y; Vs[row][c4+2]=vv4.z; Vs[row][c4+3]=vv4.w;
    }
    __syncthreads();
    #pragma unroll
    for (int kk = 0; kk < 16; ++kk) {
      float a0r = Ps[ty*4+0][kk], a1r = Ps[ty*4+1][kk], a2r = Ps[ty*4+2][kk], a3r = Ps[ty*4+3][kk];
      float b0 = Vs[kk][tx*4+0], b1 = Vs[kk][tx*4+1], b2 = Vs[kk][tx*4+2], b3 = Vs[kk][tx*4+3];
      acc[0][0]=fmaf(a0r,b0,acc[0][0]); acc[0][1]=fmaf(a0r,b1,acc[0][1]);
      acc[0][2]=fmaf(a0r,b2,acc[0][2]); acc[0][3]=fmaf(a0r,b3,acc[0][3]);
      acc[1][0]=fmaf(a1r,b0,acc[1][0]); acc[1][1]=fmaf(a1r,b1,acc[1][1]);
      acc[1][2]=fmaf(a1r,b2,acc[1][2]); acc[1][3]=fmaf(a1r,b3,acc[1][3]);
      acc[2][0]=fmaf(a2r,b0,acc[2][0]); acc[2][1]=fmaf(a2r,b1,acc[2][1]);
      acc[2][2]=fmaf(a2r,b2,acc[2][2]); acc[2][3]=fmaf(a2r,b3,acc[2][3]);
      acc[3][0]=fmaf(a3r,b0,acc[3][0]); acc[3][1]=fmaf(a3r,b1,acc[3][1]);
      acc[3][2]=fmaf(a3r,b2,acc[3][2]); acc[3][3]=fmaf(a3r,b3,acc[3][3]);
    }
    __syncthreads();
  }
  #pragma unroll
  for (int u = 0; u < 4; ++u) {
    float4 o;
    o.x = acc[u][0]; o.y = acc[u][1]; o.z = acc[u][2]; o.w = acc[u][3];
    *(float4*)(out + (size_t)(b*NSQ + c0 + ty*4 + u) * NF + f0 + tx*4) = o;
  }
}

extern "C" void kernel_launch(void* const* d_in, const int* in_sizes, int n_in,
                              void* d_out, int out_size, void* d_ws, size_t ws_size,
                              hipStream_t stream) {
  const float* x  = (const float*)d_in[0];
  const float* qw = (const float*)d_in[1];
  const float* kw = (const float*)d_in[2];
  const float* vw = (const float*)d_in[3];
  float* ws = (float*)d_ws;
  float* C  = ws;
  float* q  = ws + 3072;
  float* k  = q + (size_t)NMAT * NF;
  float* v  = k + (size_t)NMAT * NF;
  float* q2 = v + (size_t)NMAT * NF;
  float* k2 = q2 + NMAT;
  float* P  = k2 + NMAT;
  float* out = (float*)d_out;

  cayley_kernel<<<dim3(3), dim3(64), 0, stream>>>(qw, kw, vw, C);
  logm_qkv_kernel<<<dim3(NMAT), dim3(64), 0, stream>>>(x, C, q, k, v, q2, k2);
  scores_kernel<<<dim3(8, 8, NB), dim3(256), 0, stream>>>(q, k, q2, k2, P);
  softmax_kernel<<<dim3(NB * 8), dim3(256), 0, stream>>>(P);
  out_gemm_kernel<<<dim3(16, 8, NB), dim3(256), 0, stream>>>(P, v, out);
}